// Round 17
// baseline (389.793 us; speedup 1.0000x reference)
//
#include <hip/hip_runtime.h>
#include <hip/hip_bf16.h>
#include <math.h>

#define NN 50000      // nodes
#define NE 800000     // edges (without self loops)
#define NEP 850000    // edges + self loops
#define NG 64         // graphs
#define CAP 64        // bucket capacity per node

typedef unsigned short u16;
typedef __attribute__((ext_vector_type(8))) short short8;
typedef __attribute__((ext_vector_type(4))) float f32x4;

__device__ __forceinline__ float bfu2f(u16 u) {
    return __uint_as_float((unsigned)u << 16);
}
__device__ __forceinline__ u16 f2bfu(float f) {
    __hip_bfloat16 h = __float2bfloat16(f);   // RTNE
    union { __hip_bfloat16 h; u16 u; } c; c.h = h; return c.u;
}

__device__ __forceinline__ unsigned fkey(float f) {
    unsigned u = __float_as_uint(f);
    return (u & 0x80000000u) ? ~u : (u | 0x80000000u);
}
__device__ __forceinline__ float fkey_inv(unsigned k) {
    return (k & 0x80000000u) ? __uint_as_float(k ^ 0x80000000u) : __uint_as_float(~k);
}

// ================= init: seed self-loops + zero srcsort + zero pools || weight prep =================
// srcsort stored as u32 words (2 u16 slots each); word 0 of each bucket seeded with the
// self-loop id (low half) by a plain store, all other words zeroed (atomicOr targets).
__global__ void k_init(int* __restrict__ deg, unsigned* __restrict__ srcsort32,
                       int* __restrict__ poolbuf, int IB,
                       const float* __restrict__ W0, const float* __restrict__ as0, const float* __restrict__ ad0,
                       u16* __restrict__ Wb0, float* __restrict__ wa0, float* __restrict__ wb0,
                       const float* __restrict__ W1, const float* __restrict__ as1, const float* __restrict__ ad1,
                       u16* __restrict__ Wb1, float* __restrict__ wa1, float* __restrict__ wb1,
                       const float* __restrict__ W2, const float* __restrict__ as2, const float* __restrict__ ad2,
                       u16* __restrict__ Wb2, float* __restrict__ wa2, float* __restrict__ wb2) {
    __shared__ float pas[4], pbs[4];
    int tid = threadIdx.x;
    if (blockIdx.x < IB) {
        int i = blockIdx.x * 256 + tid;
        if (i < NN) {
            deg[i] = 1;                       // self-loop pre-seeded
            srcsort32[i << 5] = (unsigned)i;  // slot 0 = self, slot 1 = 0 (OR target)
        } else if (i - NN < NG * 512 + NG) {
            poolbuf[i - NN] = 0;
        }
        // zero all non-word0 bucket words (grid-stride over IB blocks)
        for (int w = blockIdx.x * 256 + tid; w < NN * 32; w += IB * 256)
            if (w & 31) srcsort32[w] = 0;
        return;
    }
    int b = blockIdx.x - IB;
    const float *W, *asv, *adv; u16* Wb; float *wa, *wb; int k, dout;
    if (b < 128)      { W = W0; asv = as0; adv = ad0; Wb = Wb0; wa = wa0; wb = wb0; k = b;       dout = 64;  }
    else if (b < 192) { W = W1; asv = as1; adv = ad1; Wb = Wb1; wa = wa1; wb = wb1; k = b - 128; dout = 128; }
    else              { W = W2; asv = as2; adv = ad2; Wb = Wb2; wa = wa2; wb = wb2; k = b - 192; dout = 256; }
    float pa = 0.f, pb = 0.f;
    for (int n = tid; n < dout; n += 256) {
        float w = W[(size_t)k * dout + n];
        Wb[(size_t)k * dout + n] = f2bfu(w);
        pa += w * asv[n];
        pb += w * adv[n];
    }
#pragma unroll
    for (int off = 32; off; off >>= 1) {
        pa += __shfl_xor(pa, off);
        pb += __shfl_xor(pb, off);
    }
    if ((tid & 63) == 0) { pas[tid >> 6] = pa; pbs[tid >> 6] = pb; }
    __syncthreads();
    if (tid == 0) {
        wa[k] = pas[0] + pas[1] + pas[2] + pas[3];
        wb[k] = pbs[0] + pbs[1] + pbs[2] + pbs[3];
    }
}

// ================= MFMA GEMM body (optional bias) =================
template<int DIN, int DOUT, bool XF32>
__device__ __forceinline__ void gemm_body(int bx, const void* __restrict__ Xin,
                                          const u16* __restrict__ Wb,
                                          u16* __restrict__ Hb,
                                          const float* __restrict__ bias) {
    constexpr int KS = DIN / 32;
    constexpr int CT = DOUT / 16;
    constexpr int TPW = CT / 4;
    constexpr int STRIDE = DIN + 16;
    __shared__ u16 Xs[64 * STRIDE];
    int tid = threadIdx.x, wave = tid >> 6, lane = tid & 63;
    int quad = lane >> 4, l15 = lane & 15;
    int n0 = bx * 64;

    short8 bfr[TPW][KS];
#pragma unroll
    for (int ct = 0; ct < TPW; ct++) {
        int nb = (wave * TPW + ct) * 16 + l15;
#pragma unroll
        for (int ks = 0; ks < KS; ks++) {
            int kb = ks * 32 + quad * 8;
            short8 b;
#pragma unroll
            for (int j = 0; j < 8; j++) b[j] = (short)Wb[(size_t)(kb + j) * DOUT + nb];
            bfr[ct][ks] = b;
        }
    }

    for (int c = tid; c < 64 * DIN / 8; c += 256) {
        int row = (c * 8) / DIN, col = (c * 8) % DIN;
        int rg = n0 + row; if (rg >= NN) rg = NN - 1;
        u16 v[8];
        if constexpr (XF32) {
            const float* p = (const float*)Xin + (size_t)rg * DIN + col;
            float4 f0 = *(const float4*)p;
            float4 f1 = *(const float4*)(p + 4);
            v[0] = f2bfu(f0.x); v[1] = f2bfu(f0.y); v[2] = f2bfu(f0.z); v[3] = f2bfu(f0.w);
            v[4] = f2bfu(f1.x); v[5] = f2bfu(f1.y); v[6] = f2bfu(f1.z); v[7] = f2bfu(f1.w);
        } else {
            const u16* p = (const u16*)Xin + (size_t)rg * DIN + col;
            ushort4 a = *(const ushort4*)p;
            ushort4 b = *(const ushort4*)(p + 4);
            v[0] = a.x; v[1] = a.y; v[2] = a.z; v[3] = a.w;
            v[4] = b.x; v[5] = b.y; v[6] = b.z; v[7] = b.w;
        }
        u16* d = &Xs[row * STRIDE + col];
#pragma unroll
        for (int j = 0; j < 8; j++) d[j] = v[j];
    }
    __syncthreads();

#pragma unroll
    for (int rt = 0; rt < 4; rt++) {
        short8 afr[KS];
#pragma unroll
        for (int ks = 0; ks < KS; ks++)
            afr[ks] = *(const short8*)&Xs[(rt * 16 + l15) * STRIDE + ks * 32 + quad * 8];
#pragma unroll
        for (int ct = 0; ct < TPW; ct++) {
            f32x4 cf = {0.f, 0.f, 0.f, 0.f};
#pragma unroll
            for (int ks = 0; ks < KS; ks++)
                cf = __builtin_amdgcn_mfma_f32_16x16x32_bf16(afr[ks], bfr[ct][ks], cf, 0, 0, 0);
            int col = (wave * TPW + ct) * 16 + l15;
            float bv = bias ? bias[col] : 0.f;
            int rbase = n0 + rt * 16 + quad * 4;
#pragma unroll
            for (int reg = 0; reg < 4; reg++) {
                int r = rbase + reg;
                if (r < NN) Hb[(size_t)r * DOUT + col] = f2bfu(cf[reg] + bv);
            }
        }
    }
}

// ================= front: edge scatter (atomicOr) || layer-1 GEMM || layer-1 s,t =================
__global__ __launch_bounds__(256) void k_front(const int* __restrict__ src, const int* __restrict__ dst,
                                               int* __restrict__ deg, unsigned* __restrict__ srcsort32,
                                               int SB, int GB,
                                               const float* __restrict__ x_in,
                                               const u16* __restrict__ Wb0, u16* __restrict__ Hb,
                                               const float* __restrict__ wa, const float* __restrict__ wb,
                                               float* __restrict__ s, float* __restrict__ t) {
    int tid = threadIdx.x;
    if (blockIdx.x < SB) {
        int i = blockIdx.x * 256 + tid;
        if (i >= NE) return;
        int sv = src[i];
        int dv = dst[i];
        int pos = atomicAdd(&deg[dv], 1);
        if (pos < CAP) {
            unsigned val = (unsigned)(u16)sv << (16 * (pos & 1));
            atomicOr(&srcsort32[(dv << 5) + (pos >> 1)], val);
        }
        return;
    }
    if (blockIdx.x < SB + GB) {
        gemm_body<128, 64, true>(blockIdx.x - SB, x_in, Wb0, Hb, nullptr);
        return;
    }
    int node = (blockIdx.x - SB - GB) * 4 + (tid >> 6);
    int lane = tid & 63;
    if (node >= NN) return;
    const float* p = x_in + (size_t)node * 128 + lane * 2;
    float x0 = p[0], x1 = p[1];
    float pa = x0 * wa[lane * 2] + x1 * wa[lane * 2 + 1];
    float pb = x0 * wb[lane * 2] + x1 * wb[lane * 2 + 1];
#pragma unroll
    for (int off = 32; off; off >>= 1) {
        pa += __shfl_xor(pa, off);
        pb += __shfl_xor(pb, off);
    }
    if (lane == 0) { s[node] = pa; t[node] = pb; }
}

// ================= standalone MFMA GEMM with bias =================
template<int DIN, int DOUT>
__global__ __launch_bounds__(256) void k_gemm_b(const u16* __restrict__ Xin,
                                                const u16* __restrict__ Wb,
                                                u16* __restrict__ Hb,
                                                const float* __restrict__ bias) {
    gemm_body<DIN, DOUT, false>(blockIdx.x, Xin, Wb, Hb, bias);
}

// ================= s,t from bf16 features (wave per node, DIN=128) =================
__global__ void k_stHb(const u16* __restrict__ X, const float* __restrict__ wa,
                       const float* __restrict__ wb, float* __restrict__ s,
                       float* __restrict__ t) {
    int node = blockIdx.x * 4 + (threadIdx.x >> 6);
    int lane = threadIdx.x & 63;
    if (node >= NN) return;
    unsigned u = *(const unsigned*)(X + (size_t)node * 128 + lane * 2);
    float x0 = bfu2f((u16)(u & 0xffff)), x1 = bfu2f((u16)(u >> 16));
    float pa = x0 * wa[lane * 2] + x1 * wa[lane * 2 + 1];
    float pb = x0 * wb[lane * 2] + x1 * wb[lane * 2 + 1];
#pragma unroll
    for (int off = 32; off; off >>= 1) {
        pa += __shfl_xor(pa, off);
        pb += __shfl_xor(pb, off);
    }
    if (lane == 0) { s[node] = pa; t[node] = pb; }
}

// ================= L1 aggregation: gather H1(64) + bias + fused next proj =================
__global__ void k_agg1(const int* __restrict__ deg, const u16* __restrict__ srcsort,
                       const float* __restrict__ s, const float* __restrict__ t,
                       const u16* __restrict__ Hb, const float* __restrict__ bias,
                       u16* __restrict__ OUT, const float* __restrict__ wan,
                       const float* __restrict__ wbn, float* __restrict__ sout,
                       float* __restrict__ tout) {
    constexpr int GS = 8;   // 64/8
    constexpr int P  = 8;
    int node = blockIdx.x * 4 + (threadIdx.x >> 6);
    int lane = threadIdx.x & 63;
    if (node >= NN) return;
    int cnt = min(deg[node], CAP);
    float tn = t[node];
    int sv = 0; float ex = 0.f;
    if (lane < cnt) {
        sv = srcsort[(node << 6) + lane];
        float e = s[sv] + tn;
        e = (e > 0.f) ? e : 0.2f * e;
        ex = expf(e);
    }
    float dsum = ex;
#pragma unroll
    for (int off = 32; off; off >>= 1) dsum += __shfl_xor(dsum, off);
    ex *= 1.f / dsum;

    int sg = lane / GS;
    int pg = lane % GS;
    float acc[8];
#pragma unroll
    for (int e = 0; e < 8; e++) acc[e] = 0.f;

    for (int q = 0; q < cnt; q += P) {
        int myq = q + sg;
        int mq = (myq < cnt) ? myq : q;
        float a = __shfl(ex, mq);
        int  idx = __shfl(sv, mq);
        if (myq >= cnt) a = 0.f;
        uint4 u = *(const uint4*)(Hb + (size_t)idx * 64 + pg * 8);
        acc[0] += a * bfu2f((u16)(u.x & 0xffff));
        acc[1] += a * bfu2f((u16)(u.x >> 16));
        acc[2] += a * bfu2f((u16)(u.y & 0xffff));
        acc[3] += a * bfu2f((u16)(u.y >> 16));
        acc[4] += a * bfu2f((u16)(u.z & 0xffff));
        acc[5] += a * bfu2f((u16)(u.z >> 16));
        acc[6] += a * bfu2f((u16)(u.w & 0xffff));
        acc[7] += a * bfu2f((u16)(u.w >> 16));
    }

#pragma unroll
    for (int step = GS; step < 64; step <<= 1) {
#pragma unroll
        for (int e = 0; e < 8; e++) acc[e] += __shfl_xor(acc[e], step);
    }
#pragma unroll
    for (int e = 0; e < 8; e++) acc[e] += bias[pg * 8 + e];

    {
        float pa = 0.f, pb = 0.f;
#pragma unroll
        for (int e = 0; e < 8; e++) {
            pa += acc[e] * wan[pg * 8 + e];
            pb += acc[e] * wbn[pg * 8 + e];
        }
#pragma unroll
        for (int off = 32; off; off >>= 1) {
            pa += __shfl_xor(pa, off);
            pb += __shfl_xor(pb, off);
        }
        if (lane == 0) { sout[node] = pa * (1.f / P); tout[node] = pb * (1.f / P); }
    }

    if (sg == 0) {
        uint4 o;
        o.x = (unsigned)f2bfu(acc[0]) | ((unsigned)f2bfu(acc[1]) << 16);
        o.y = (unsigned)f2bfu(acc[2]) | ((unsigned)f2bfu(acc[3]) << 16);
        o.z = (unsigned)f2bfu(acc[4]) | ((unsigned)f2bfu(acc[5]) << 16);
        o.w = (unsigned)f2bfu(acc[6]) | ((unsigned)f2bfu(acc[7]) << 16);
        *(uint4*)(OUT + (size_t)node * 64 + pg * 8) = o;
    }
}

// ================= pure aggregation: A[dst] = sum alpha * X[src] (pre-GEMM) =================
template<int DIN>
__global__ void k_aggX(const int* __restrict__ deg, const u16* __restrict__ srcsort,
                       const float* __restrict__ s, const float* __restrict__ t,
                       const u16* __restrict__ X, u16* __restrict__ OUT) {
    constexpr int GS = DIN / 8;
    constexpr int P  = 64 / GS;
    int node = blockIdx.x * 4 + (threadIdx.x >> 6);
    int lane = threadIdx.x & 63;
    if (node >= NN) return;
    int cnt = min(deg[node], CAP);
    float tn = t[node];
    int sv = 0; float ex = 0.f;
    if (lane < cnt) {
        sv = srcsort[(node << 6) + lane];
        float e = s[sv] + tn;
        e = (e > 0.f) ? e : 0.2f * e;
        ex = expf(e);
    }
    float dsum = ex;
#pragma unroll
    for (int off = 32; off; off >>= 1) dsum += __shfl_xor(dsum, off);
    ex *= 1.f / dsum;

    int sg = lane / GS;
    int pg = lane % GS;
    float acc[8];
#pragma unroll
    for (int e = 0; e < 8; e++) acc[e] = 0.f;

    for (int q = 0; q < cnt; q += P) {
        int myq = q + sg;
        int mq = (myq < cnt) ? myq : q;
        float a = __shfl(ex, mq);
        int  idx = __shfl(sv, mq);
        if (myq >= cnt) a = 0.f;
        uint4 u = *(const uint4*)(X + (size_t)idx * DIN + pg * 8);
        acc[0] += a * bfu2f((u16)(u.x & 0xffff));
        acc[1] += a * bfu2f((u16)(u.x >> 16));
        acc[2] += a * bfu2f((u16)(u.y & 0xffff));
        acc[3] += a * bfu2f((u16)(u.y >> 16));
        acc[4] += a * bfu2f((u16)(u.z & 0xffff));
        acc[5] += a * bfu2f((u16)(u.z >> 16));
        acc[6] += a * bfu2f((u16)(u.w & 0xffff));
        acc[7] += a * bfu2f((u16)(u.w >> 16));
    }

#pragma unroll
    for (int step = GS; step < 64; step <<= 1) {
#pragma unroll
        for (int e = 0; e < 8; e++) acc[e] += __shfl_xor(acc[e], step);
    }

    if (sg == 0) {
        uint4 o;
        o.x = (unsigned)f2bfu(acc[0]) | ((unsigned)f2bfu(acc[1]) << 16);
        o.y = (unsigned)f2bfu(acc[2]) | ((unsigned)f2bfu(acc[3]) << 16);
        o.z = (unsigned)f2bfu(acc[4]) | ((unsigned)f2bfu(acc[5]) << 16);
        o.w = (unsigned)f2bfu(acc[6]) | ((unsigned)f2bfu(acc[7]) << 16);
        *(uint4*)(OUT + (size_t)node * DIN + pg * 8) = o;
    }
}

// ================= pooling (bf16 input) =================
__global__ void k_pool2(const u16* __restrict__ H, const int* __restrict__ batch,
                        unsigned* __restrict__ x1k, float* __restrict__ x2,
                        float* __restrict__ cnt) {
    int c0 = blockIdx.x * 64;
    if (c0 >= NN) return;
    int o = threadIdx.x;
    int endn = min(c0 + 64, NN);
    int g = batch[c0];
    float mx = -INFINITY, sm = 0.f, cl = 0.f;
    for (int nd = c0; nd < endn; nd++) {
        int bg = batch[nd];
        if (bg != g) {
            atomicMax(&x1k[g * 256 + o], fkey(mx));
            atomicAdd(&x2[g * 256 + o], sm);
            if (o == 0) atomicAdd(&cnt[g], cl);
            g = bg; mx = -INFINITY; sm = 0.f; cl = 0.f;
        }
        float hv = bfu2f(H[(size_t)nd * 256 + o]);
        mx = fmaxf(mx, hv);
        sm += hv;
        cl += 1.f;
    }
    atomicMax(&x1k[g * 256 + o], fkey(mx));
    atomicAdd(&x2[g * 256 + o], sm);
    if (o == 0) atomicAdd(&cnt[g], cl);
}

// ================= fused dense tail =================
template<int DIN, int DOUT, int ACT>
__device__ __forceinline__ void dense_layer(const float* __restrict__ in,
                                            const float* __restrict__ W,
                                            const float* __restrict__ B,
                                            float* __restrict__ out, int o,
                                            float* __restrict__ red) {
    constexpr int T = 256 / DOUT;
    constexpr int KS = DIN / T;
    int oo = o % DOUT;
    int kk = o / DOUT;
    int kbase = kk * KS;
    float p0 = 0.f, p1 = 0.f, p2 = 0.f, p3 = 0.f;
#pragma unroll 4
    for (int k = 0; k < KS; k += 4) {
        p0 += in[kbase + k]     * W[(size_t)(kbase + k) * DOUT + oo];
        p1 += in[kbase + k + 1] * W[(size_t)(kbase + k + 1) * DOUT + oo];
        p2 += in[kbase + k + 2] * W[(size_t)(kbase + k + 2) * DOUT + oo];
        p3 += in[kbase + k + 3] * W[(size_t)(kbase + k + 3) * DOUT + oo];
    }
    float p = (p0 + p1) + (p2 + p3);
    if constexpr (T > 1) {
        red[o] = p;
        __syncthreads();
        if (o < DOUT) {
#pragma unroll
            for (int tt = 1; tt < T; tt++) p += red[oo + tt * DOUT];
        }
    }
    if (o < DOUT) {
        p += B[oo];
        if constexpr (ACT == 1) p = fmaxf(p, 0.f);
        else if constexpr (ACT == 2) p = 1.f / (1.f + expf(-p));
        out[oo] = p;
    }
    __syncthreads();
}

__global__ void k_tail(const unsigned* __restrict__ x1k, const float* __restrict__ x2,
                       const float* __restrict__ cnt,
                       const float* __restrict__ d1w, const float* __restrict__ d1b,
                       const float* __restrict__ d2w, const float* __restrict__ d2b,
                       const float* __restrict__ d3w, const float* __restrict__ d3b,
                       const float* __restrict__ mw,  const float* __restrict__ mb,
                       const float* __restrict__ d4w, const float* __restrict__ d4b,
                       const float* __restrict__ d5w, const float* __restrict__ d5b,
                       const float* __restrict__ d6w, const float* __restrict__ d6b,
                       const float* __restrict__ d7w, const float* __restrict__ d7b,
                       float* __restrict__ out) {
    __shared__ float z[512];
    __shared__ float A[256];
    __shared__ float Bf[256];
    __shared__ float red[256];
    __shared__ float x3s[256];
    __shared__ float gbuf[64];
    int g = blockIdx.x, o = threadIdx.x;
    float c = fmaxf(cnt[g], 1.f);
    float sv = x2[(size_t)g * 256 + o];
    z[o] = fkey_inv(x1k[(size_t)g * 256 + o]);
    z[256 + o] = sv;
    x3s[o] = sv / c;
    __syncthreads();
    dense_layer<512, 256, 1>(z,   d1w, d1b, A,    o, red);
    dense_layer<256, 128, 1>(A,   d2w, d2b, Bf,   o, red);
    dense_layer<128,  64, 1>(Bf,  d3w, d3b, A,    o, red);
    dense_layer<256,  64, 2>(x3s, mw,  mb,  gbuf, o, red);
    if (o < 64) A[o] *= gbuf[o];
    __syncthreads();
    dense_layer< 64,  64, 1>(A,   d4w, d4b, Bf,   o, red);
    dense_layer< 64, 128, 1>(Bf,  d5w, d5b, A,    o, red);
    dense_layer<128, 256, 1>(A,   d6w, d6b, z,    o, red);
    dense_layer<256, 128, 0>(z,   d7w, d7b, A,    o, red);
    if (o < 128) out[(size_t)g * 128 + o] = A[o];
}

// =====================================================================
extern "C" void kernel_launch(void* const* d_in, const int* in_sizes, int n_in,
                              void* d_out, int out_size, void* d_ws, size_t ws_size,
                              hipStream_t stream) {
    const float* x_in  = (const float*)d_in[0];
    const int*   ei    = (const int*)d_in[1];
    const int*   batch = (const int*)d_in[2];
    const int* src = ei;
    const int* dst = ei + NE;

    const float* Wl[3]  = { (const float*)d_in[3], (const float*)d_in[7],  (const float*)d_in[11] };
    const float* asl[3] = { (const float*)d_in[4], (const float*)d_in[8],  (const float*)d_in[12] };
    const float* adl[3] = { (const float*)d_in[5], (const float*)d_in[9],  (const float*)d_in[13] };
    const float* bl[3]  = { (const float*)d_in[6], (const float*)d_in[10], (const float*)d_in[14] };

    const float* d1w = (const float*)d_in[15]; const float* d1b = (const float*)d_in[16];
    const float* d2w = (const float*)d_in[17]; const float* d2b = (const float*)d_in[18];
    const float* d3w = (const float*)d_in[19]; const float* d3b = (const float*)d_in[20];
    const float* mw  = (const float*)d_in[21]; const float* mb  = (const float*)d_in[22];
    const float* d4w = (const float*)d_in[23]; const float* d4b = (const float*)d_in[24];
    const float* d5w = (const float*)d_in[25]; const float* d5b = (const float*)d_in[26];
    const float* d6w = (const float*)d_in[27]; const float* d6b = (const float*)d_in[28];
    const float* d7w = (const float*)d_in[29]; const float* d7b = (const float*)d_in[30];

    // -------- workspace carve --------
    float* ws = (float*)d_ws;
    size_t off = 0;
    u16* Hb1 = (u16*)(ws + off); off += (size_t)NN * 32;    // L1 H (64-dim bf16)
    u16* Xb1 = (u16*)(ws + off); off += (size_t)NN * 32;    // L1 out (64)
    u16* A2  = (u16*)(ws + off); off += (size_t)NN * 32;    // L2 aggregated input (64)
    u16* H2  = (u16*)(ws + off); off += (size_t)NN * 64;    // L2 out (128)
    u16* A3  = (u16*)(ws + off); off += (size_t)NN * 64;    // L3 aggregated input (128)
    u16* Xb3 = (u16*)(ws + off); off += (size_t)NN * 128;   // L3 out (256)
    float* sA = ws + off; off += NN;
    float* tA = ws + off; off += NN;
    float* sB = ws + off; off += NN;
    float* tB = ws + off; off += NN;
    u16* Wb0 = (u16*)(ws + off); off += (128 * 64) / 2;
    u16* Wb1 = (u16*)(ws + off); off += (64 * 128) / 2;
    u16* Wb2 = (u16*)(ws + off); off += (128 * 256) / 2;
    float* wa0 = ws + off; off += 128;  float* wb0 = ws + off; off += 128;
    float* wa1 = ws + off; off += 64;   float* wb1 = ws + off; off += 64;
    float* wa2 = ws + off; off += 128;  float* wb2 = ws + off; off += 128;
    unsigned* x1k = (unsigned*)(ws + off); off += NG * 256;
    float* x2    = ws + off; off += NG * 256;
    float* cnt   = ws + off; off += NG;
    int* ip      = (int*)(ws + off);
    int* deg     = ip;               ip += NN;
    unsigned* srcsort32 = (unsigned*)ip;  ip += NN * 32;   // bucket CSR as u32 words
    u16* srcsort = (u16*)srcsort32;

    const int GB = (NN + 63) / 64;      // gemm blocks (782)
    const int AB = (NN + 3) / 4;        // agg/st blocks (12500)
    const int SB = (NE + 255) / 256;    // scatter blocks (3125)
    const int IB = (NN + NG * 512 + NG + 255) / 256;

    // -------- front --------
    k_init<<<IB + 320, 256, 0, stream>>>(deg, srcsort32, (int*)x1k, IB,
                                         Wl[0], asl[0], adl[0], Wb0, wa0, wb0,
                                         Wl[1], asl[1], adl[1], Wb1, wa1, wb1,
                                         Wl[2], asl[2], adl[2], Wb2, wa2, wb2);
    k_front<<<SB + GB + AB, 256, 0, stream>>>(src, dst, deg, srcsort32, SB, GB,
                                              x_in, Wb0, Hb1, wa0, wb0, sA, tA);

    // -------- layer 1: gather H1 + b1 -> Xb1; fused s2,t2 --------
    k_agg1<<<AB, 256, 0, stream>>>(deg, srcsort, sA, tA, Hb1, bl[0], Xb1, wa1, wb1, sB, tB);

    // -------- layer 2: aggregate X (64) then GEMM(+b2); s3,t3 from H2 --------
    k_aggX<64><<<AB, 256, 0, stream>>>(deg, srcsort, sB, tB, Xb1, A2);
    k_gemm_b<64, 128><<<GB, 256, 0, stream>>>(A2, Wb1, H2, bl[1]);
    k_stHb<<<AB, 256, 0, stream>>>(H2, wa2, wb2, sA, tA);

    // -------- layer 3: aggregate X (128) then GEMM(+b3) --------
    k_aggX<128><<<AB, 256, 0, stream>>>(deg, srcsort, sA, tA, H2, A3);
    k_gemm_b<128, 256><<<GB, 256, 0, stream>>>(A3, Wb2, Xb3, bl[2]);

    // -------- pooling + fused tail --------
    k_pool2<<<(NN + 63) / 64, 256, 0, stream>>>(Xb3, batch, x1k, x2, cnt);
    k_tail<<<NG, 256, 0, stream>>>(x1k, x2, cnt,
                                   d1w, d1b, d2w, d2b, d3w, d3b, mw, mb,
                                   d4w, d4b, d5w, d5b, d6w, d6b, d7w, d7b,
                                   (float*)d_out);
}